// Round 20
// baseline (173.166 us; speedup 1.0000x reference)
//
#include <hip/hip_runtime.h>
#include <cstddef>

// MultiHeadAttentionLayer: B=2, S=2048, D=1024, H=16, DEPTH=64
// R19 (from R17/18 = 119.3us): fuse the q/k/v f32->bf16 conversion INTO
//      proj's A-staging (reg-staged float4 loads -> swizzled ushort4 LDS
//      writes), deleting the 24MB bf16 intermediate write + re-read and the
//      separate 48MB cvt pass. R4's version of this serialized at 3
//      blocks/CU; R17's 6-blocks/CU TLP is the antidote. prep shrinks to
//      the W-transpose only (~3us). attn32 / gemm_o byte-identical to R18.

namespace {

constexpr int Ss = 2048;
constexpr int Dd = 1024;
constexpr int Mm = 4096;  // B*S
constexpr float QSCALE = 0.18033688f;   // 0.125 / ln2  (base-2 softmax)
constexpr float NEG2 = -1.442695041e9f; // -1e9 / ln2

typedef unsigned short u16;
typedef __attribute__((ext_vector_type(8))) __bf16 bf16x8;
typedef __attribute__((ext_vector_type(4))) float f32x4;
typedef __attribute__((ext_vector_type(16))) float f32x16;
typedef __attribute__((ext_vector_type(4))) unsigned int u32x4;
typedef __attribute__((ext_vector_type(2))) unsigned int u32x2;
typedef __attribute__((ext_vector_type(8))) unsigned short us8;

__device__ __forceinline__ u16 bfc(float f) {
  __bf16 h = (__bf16)f;  // RNE; pairs into v_cvt_pk_bf16_f32
  return __builtin_bit_cast(u16, h);
}
__device__ __forceinline__ unsigned pack2(float lo, float hi) {
  return (unsigned)bfc(lo) | ((unsigned)bfc(hi) << 16);
}

__device__ __forceinline__ void gload_lds16(const void* g, void* l) {
  __builtin_amdgcn_global_load_lds(
      (__attribute__((address_space(1))) void*)g,
      (__attribute__((address_space(3))) void*)l, 16, 0, 0);
}

__device__ __forceinline__ f32x4 mfma16(bf16x8 a, bf16x8 b, f32x4 c) {
  return __builtin_amdgcn_mfma_f32_16x16x32_bf16(a, b, c, 0, 0, 0);
}
__device__ __forceinline__ f32x16 mfma32(bf16x8 a, bf16x8 b, f32x16 c) {
  return __builtin_amdgcn_mfma_f32_32x32x16_bf16(a, b, c, 0, 0, 0);
}
__device__ __forceinline__ float exp2_fast(float x) {
  return __builtin_amdgcn_exp2f(x);
}

__device__ __forceinline__ void pl32swap(unsigned& a, unsigned& b) {
#if __has_builtin(__builtin_amdgcn_permlane32_swap)
  u32x2 r = __builtin_amdgcn_permlane32_swap(a, b, false, false);
  a = r[0];
  b = r[1];
#else
  unsigned ax = (unsigned)__shfl_xor((int)a, 32);
  unsigned bx = (unsigned)__shfl_xor((int)b, 32);
  bool hi = (threadIdx.x & 63) >= 32;
  unsigned na = hi ? bx : a;
  unsigned nb = hi ? b : ax;
  a = na;
  b = nb;
#endif
}

// counted-vmcnt barrier (T4)
#define PIPE_BARRIER_V(N)                                  \
  do {                                                     \
    asm volatile("s_waitcnt vmcnt(" #N ")" ::: "memory");  \
    __builtin_amdgcn_sched_barrier(0);                     \
    __builtin_amdgcn_s_barrier();                          \
    __builtin_amdgcn_sched_barrier(0);                     \
  } while (0)

// swizzled u16 index within a [rows][64 u16] LDS tile (128B rows, 16B chunks)
__device__ __forceinline__ int swz(int row, int col) {
  return row * 64 + ((((col >> 3) ^ (row & 7)) << 3) | (col & 7));
}
// pre-swizzled source column for global_load_lds staging of 8 rows
__device__ __forceinline__ int src_col(int lane) {
  return ((lane & 7) ^ (lane >> 3)) * 8;
}

// ---------------------------------------------------------------- prep (W only)
// W transpose (f32 KxN -> bf16 NxK), 3 weights x 32x32 tiles = 3072 blocks.
__global__ __launch_bounds__(256) void prep(const float* __restrict__ W0,
                                            const float* __restrict__ W1,
                                            const float* __restrict__ W2,
                                            u16* __restrict__ wsbase) {
  __shared__ float tile[32][33];
  const int blk = (int)blockIdx.x;
  const int tid = threadIdx.x;
  const int z = blk >> 10;
  const int rem = blk & 1023;
  const int n0 = (rem & 31) * 32;
  const int k0 = (rem >> 5) * 32;
  const float* W = (z == 0) ? W0 : (z == 1) ? W1 : W2;
  u16* WT = wsbase + (size_t)z * (1024 * 1024);
  const int tx = tid & 31;
  const int ty = tid >> 5;
#pragma unroll
  for (int i = 0; i < 4; ++i)
    tile[ty + i * 8][tx] = W[(size_t)(k0 + ty + i * 8) * 1024 + n0 + tx];
  __syncthreads();
  const int r = tid >> 3;
  const int c4 = (tid & 7) * 4;
  ushort4 o4 = make_ushort4(bfc(tile[c4 + 0][r]), bfc(tile[c4 + 1][r]),
                            bfc(tile[c4 + 2][r]), bfc(tile[c4 + 3][r]));
  *(ushort4*)(&WT[(size_t)(n0 + r) * 1024 + k0 + c4]) = o4;
}

// ---------------------------------------------------------------- fused QKV projection
// A = f32 source (q/k/v), converted in-register during staging (fused cvt).
// 128x64 tiles, grid 1536, LDS 24KB, simple 2-barrier loop, panel-grouped
// XCD swizzle. z==2 (V): masked tokens' rows ZEROED (mask folded into V).
__global__ __launch_bounds__(256) void proj_qkv(
    const float* __restrict__ qf32, const float* __restrict__ kf32,
    const float* __restrict__ vf32, const u16* __restrict__ WqT,
    const u16* __restrict__ WvT, const float* __restrict__ bq,
    const float* __restrict__ bv, const float* __restrict__ maskf,
    u16* __restrict__ Qp, u16* __restrict__ Kp, u16* __restrict__ VpT) {
  constexpr int K = 1024, N = 1024, M = 4096;
  __shared__ u16 As[128 * 64];
  __shared__ u16 Bs[64 * 64];
  const int lin = (int)blockIdx.x;        // 0..1535
  const int xcd = lin & 7;
  const int j = lin >> 3;                 // 0..191
  const int panel = xcd * 12 + (j >> 4);  // 0..95 (bijective: 12 panels/XCD)
  const int ntile = j & 15;               // 0..15
  const int z = panel >> 5;               // 0..2
  const int mtile = panel & 31;
  const int n0 = ntile * 64;
  const int m0 = mtile * 128;

  const float* A = (z == 0) ? qf32 : (z == 1) ? kf32 : vf32;
  const u16* Bt = (z == 2) ? WvT : WqT;
  const float* bias = (z == 2) ? bv : bq;
  const float cscale = (z == 0) ? QSCALE : 1.0f;

  const int tid = threadIdx.x;
  const int wid = tid >> 6;
  const int lane = tid & 63;
  const int g = lane >> 4;
  const int lr = lane & 15;
  // A-staging geometry: 128x64 f32 tile = 2048 float4 chunks; 8/thread.
  const int arow = tid >> 1;            // rows 0..127 (2 threads/row)
  const int ac4 = (tid & 1) * 32;       // each thread covers 32 cols (8 f4)

  const f32x4 zero = {0.f, 0.f, 0.f, 0.f};
  f32x4 acc[2][4];
#pragma unroll
  for (int m = 0; m < 2; ++m)
#pragma unroll
    for (int n = 0; n < 4; ++n) acc[m][n] = zero;

  for (int kt = 0; kt < 16; ++kt) {
    // issue f32 A loads first (HBM latency hides under TLP)
    float4 areg[8];
#pragma unroll
    for (int i = 0; i < 8; ++i)
      areg[i] = *(const float4*)(&A[(size_t)(m0 + arow) * K + kt * 64 + ac4 + i * 4]);
    // B: global_load_lds (pre-swizzled source)
#pragma unroll
    for (int jj = 0; jj < 2; ++jj) {
      int rb = (wid * 2 + jj) * 8;
      gload_lds16(&Bt[(size_t)(n0 + rb + (lane >> 3)) * K + kt * 64 + src_col(lane)],
                  &Bs[rb * 64]);
    }
    // convert + swizzled write of A
#pragma unroll
    for (int i = 0; i < 8; ++i) {
      ushort4 o4 = make_ushort4(bfc(areg[i].x), bfc(areg[i].y),
                                bfc(areg[i].z), bfc(areg[i].w));
      *(ushort4*)(&As[swz(arow, ac4 + i * 4)]) = o4;
    }
    __syncthreads();
#pragma unroll
    for (int kk = 0; kk < 2; ++kk) {
      bf16x8 a[2], b[4];
#pragma unroll
      for (int m = 0; m < 2; ++m)
        a[m] = *(const bf16x8*)(&As[swz(wid * 32 + m * 16 + lr, kk * 32 + g * 8)]);
#pragma unroll
      for (int n = 0; n < 4; ++n)
        b[n] = *(const bf16x8*)(&Bs[swz(n * 16 + lr, kk * 32 + g * 8)]);
#pragma unroll
      for (int m = 0; m < 2; ++m)
#pragma unroll
        for (int n = 0; n < 4; ++n) acc[m][n] = mfma16(a[m], b[n], acc[m][n]);
    }
    __syncthreads();
  }

#pragma unroll
  for (int n = 0; n < 4; ++n) {
    const int col = n0 + n * 16 + lr;
    const float bv_ = bias[col];
#pragma unroll
    for (int m = 0; m < 2; ++m) {
      const int rowb = m0 + wid * 32 + m * 16 + g * 4;
      if (z == 2) {
        const f32x4 mk = *(const f32x4*)(&maskf[rowb]);
        ushort4 o4;
        o4.x = (mk[0] != 0.f) ? (u16)0 : bfc(acc[m][n][0] + bv_);
        o4.y = (mk[1] != 0.f) ? (u16)0 : bfc(acc[m][n][1] + bv_);
        o4.z = (mk[2] != 0.f) ? (u16)0 : bfc(acc[m][n][2] + bv_);
        o4.w = (mk[3] != 0.f) ? (u16)0 : bfc(acc[m][n][3] + bv_);
        *(ushort4*)(&VpT[(size_t)col * M + rowb]) = o4;
      } else {
        u16* Cp = (z == 0) ? Qp : Kp;
#pragma unroll
        for (int r = 0; r < 4; ++r)
          Cp[(size_t)(rowb + r) * N + col] = bfc((acc[m][n][r] + bv_) * cscale);
      }
    }
  }
}

// ---------------------------------------------------------------- O-GEMM
// out = AO @ WoT^T + bo (f32). 64x64 tiles, grid 1024, simple 2-barrier
// loop, panel-grouped XCD swizzle. Wave = 32x32 quadrant via mfma32.
__global__ __launch_bounds__(256) void gemm_o(const u16* __restrict__ Ap,
                                              const u16* __restrict__ Bt,
                                              const float* __restrict__ bias,
                                              float* __restrict__ Cp) {
  constexpr int K = 1024, N = 1024;
  __shared__ u16 As[64 * 64];
  __shared__ u16 Bs[64 * 64];
  const int lin = (int)blockIdx.x;       // 0..1023
  const int xcd = lin & 7;
  const int j = lin >> 3;                // 0..127
  const int mtile = xcd * 8 + (j >> 4);  // 0..63 (bijective: 8 panels/XCD)
  const int ntile = j & 15;
  const int n0 = ntile * 64;
  const int m0 = mtile * 64;

  const int tid = threadIdx.x;
  const int wid = tid >> 6;
  const int lane = tid & 63;
  const int l31 = lane & 31;
  const int hi = lane >> 5;
  const int wr = wid >> 1, wc = wid & 1;

  f32x16 acc;
#pragma unroll
  for (int r = 0; r < 16; ++r) acc[r] = 0.f;

  for (int kt = 0; kt < 16; ++kt) {
#pragma unroll
    for (int jj = 0; jj < 2; ++jj) {
      const int rb = (wid * 2 + jj) * 8;
      gload_lds16(&Ap[(size_t)(m0 + rb + (lane >> 3)) * K + kt * 64 + src_col(lane)],
                  &As[rb * 64]);
      gload_lds16(&Bt[(size_t)(n0 + rb + (lane >> 3)) * K + kt * 64 + src_col(lane)],
                  &Bs[rb * 64]);
    }
    __syncthreads();
#pragma unroll
    for (int d = 0; d < 4; ++d) {
      bf16x8 af = *(const bf16x8*)(&As[swz(wr * 32 + l31, d * 16 + hi * 8)]);
      bf16x8 bf = *(const bf16x8*)(&Bs[swz(wc * 32 + l31, d * 16 + hi * 8)]);
      acc = mfma32(af, bf, acc);
    }
    __syncthreads();
  }
  // C/D: col = lane&31 (n), row = (r&3)+8*(r>>2)+4*hi (m)
  const int col = n0 + wc * 32 + l31;
  const float bv_ = bias[col];
#pragma unroll
  for (int r = 0; r < 16; ++r) {
    const int row = m0 + wr * 32 + (r & 3) + 8 * (r >> 2) + 4 * hi;
    Cp[(size_t)row * N + col] = acc[r] + bv_;
  }
}

// ---------------------------------------------------------------- attention
// 8-wave key-split flash attention, PAIR-TILE iterations (16 barriers).
// Block = 128 q-rows (512 thr); wave (qq=wid&3, kh=wid>>2) = 32 q-rows x
// 32-key half per 64-key tile. Mask bias folded into QK C-init (base-2);
// p underflows to 0 for masked keys; l = VALU row-sum tree. 4-buffer LDS.
__global__ __launch_bounds__(512) void attn32(const u16* __restrict__ Qp,
                                              const u16* __restrict__ Kp,
                                              const u16* __restrict__ VpT,
                                              const float* __restrict__ mask,
                                              u16* __restrict__ Op) {
  __shared__ u16 smem[8 * 64 * 64];  // 64 KB: K bufs 0..3, V bufs 4..7 (x4096 u16)
  __shared__ float msall[Ss];        // 8 KB mask * NEG2
  const int tid = threadIdx.x;
  const int wid = tid >> 6;          // 0..7
  const int lane = tid & 63;
  const int l31 = lane & 31;
  const int hi = lane >> 5;
  const int qq = wid & 3;
  const int kh = wid >> 2;           // key-half this wave owns
  const int lin = (int)(blockIdx.x + (blockIdx.y << 4));  // grid (16,32)
  const int wl = (lin & 7) * 64 + (lin >> 3);             // XCD-bijective
  const int qt = wl & 15;
  const int bh = wl >> 4;
  const int b = bh >> 4;
  const int h = bh & 15;
  const int q0 = qt * 128;
  const size_t base = ((size_t)b * Ss) * Dd + (size_t)h * 64;
  const size_t vbase = (size_t)h * 64 * Mm + (size_t)b * Ss;
  const int qrow = q0 + qq * 32 + l31;

  auto stageKV = [&](int t, int buf) {
    const int key0 = t * 64;
    const int rb = wid * 8;  // 8 waves x 8 rows = 64 rows each of K and V^T
    gload_lds16(&Kp[base + (size_t)(key0 + rb + (lane >> 3)) * Dd + src_col(lane)],
                smem + buf * 4096 + rb * 64);
    gload_lds16(&VpT[vbase + (size_t)(rb + (lane >> 3)) * Mm + key0 + src_col(lane)],
                smem + (4 + buf) * 4096 + rb * 64);
  };

  // prologue: mask + qf loads (drained here), then staging (stays in flight)
  const float4 mk = *(const float4*)(&mask[(size_t)b * Ss + tid * 4]);
  bf16x8 qf[4];
#pragma unroll
  for (int d = 0; d < 4; ++d)
    qf[d] = *(const bf16x8*)(&Qp[base + (size_t)qrow * Dd + d * 16 + hi * 8]);

  stageKV(0, 0);  // tiles 0,1 -> bufs 0,1 (4 loads in flight)
  stageKV(1, 1);

  {
    f32x4 s = {mk.x * NEG2, mk.y * NEG2, mk.z * NEG2, mk.w * NEG2};
    *(f32x4*)(&msall[tid * 4]) = s;
  }
  asm volatile("s_waitcnt lgkmcnt(0)" ::: "memory");
  __builtin_amdgcn_sched_barrier(0);
  __builtin_amdgcn_s_barrier();
  __builtin_amdgcn_sched_barrier(0);

  f32x16 oacc[2];
#pragma unroll
  for (int i = 0; i < 2; ++i)
#pragma unroll
    for (int r = 0; r < 16; ++r) oacc[i][r] = 0.f;
  float lsum = 0.f;

  for (int i = 0; i < 16; ++i) {
    // pair i's loads were issued a full compute phase ago -> cheap drain
    PIPE_BARRIER_V(0);
    if (i < 15) {
      stageKV(2 * i + 2, (2 * i + 2) & 3);  // bufs freed by iter i-1 (barrier-proven)
      stageKV(2 * i + 3, (2 * i + 3) & 3);
    }
#pragma unroll
    for (int u = 0; u < 2; ++u) {
      const int t = 2 * i + u;
      const int buf = t & 3;
      const u16* ks = smem + buf * 4096;
      const u16* vt = smem + (4 + buf) * 4096;
      const float* msp = &msall[t * 64 + kh * 32];

      // S^T = K Q^T with C-init = mask bias (broadcast f32x4 reads).
      // key(r,hi) = kh*32 + (r&3) + 8*(r>>2) + 4*hi  (r = a*4+j)
      f32x16 sacc;
#pragma unroll
      for (int a = 0; a < 4; ++a) {
        const f32x4 mv = *(const f32x4*)(&msp[a * 8 + hi * 4]);
#pragma unroll
        for (int jj = 0; jj < 4; ++jj) sacc[a * 4 + jj] = mv[jj];
      }
      __builtin_amdgcn_s_setprio(1);
#pragma unroll
      for (int d = 0; d < 4; ++d) {
        bf16x8 kf = *(const bf16x8*)(&ks[swz(kh * 32 + l31, d * 16 + hi * 8)]);
        sacc = mfma32(kf, qf[d], sacc);
      }
      __builtin_amdgcn_s_setprio(0);

      // p = exp2(s + bias): masked keys -> exactly 0
#pragma unroll
      for (int r = 0; r < 16; ++r) sacc[r] = exp2_fast(sacc[r]);

      // l: VALU row-sum tree (qrow = l31) + cross-hi shuffle
      {
        float sm[8];
#pragma unroll
        for (int r = 0; r < 8; ++r) sm[r] = sacc[r] + sacc[r + 8];
#pragma unroll
        for (int s = 4; s >= 1; s >>= 1)
#pragma unroll
          for (int r = 0; r < s; ++r) sm[r] += sm[r + s];
        lsum += sm[0] + __shfl_xor(sm[0], 32);
      }

      // pack P -> bf16 A-fragments (T12)
      bf16x8 pa[2];
#pragma unroll
      for (int slot = 0; slot < 2; ++slot) {
        const int bse = slot * 8;
        unsigned A0 = pack2(sacc[bse + 0], sacc[bse + 1]);
        unsigned A1 = pack2(sacc[bse + 2], sacc[bse + 3]);
        unsigned B0 = pack2(sacc[bse + 4], sacc[bse + 5]);
        unsigned B1 = pack2(sacc[bse + 6], sacc[bse + 7]);
        pl32swap(A0, B0);
        pl32swap(A1, B1);
        u32x4 w = {A0, A1, B0, B1};
        pa[slot] = __builtin_bit_cast(bf16x8, w);
      }

      // O += P V
      __builtin_amdgcn_s_setprio(1);
#pragma unroll
      for (int slot = 0; slot < 2; ++slot)
#pragma unroll
        for (int dsub = 0; dsub < 2; ++dsub) {
          bf16x8 vf = *(const bf16x8*)(
              &vt[swz(dsub * 32 + l31, kh * 32 + slot * 16 + hi * 8)]);
          oacc[dsub] = mfma32(pa[slot], vf, oacc[dsub]);
        }
      __builtin_amdgcn_s_setprio(0);
    }
  }

  // cross-wave (kh) combine through the dead K/V buffers.
  __syncthreads();
  float* rbuf = (float*)smem;   // 16384 floats available
  if (kh == 1) {
    float* p = rbuf + qq * 3072 + lane;
#pragma unroll
    for (int r = 0; r < 16; ++r) p[r * 64] = oacc[0][r];
#pragma unroll
    for (int r = 0; r < 16; ++r) p[(16 + r) * 64] = oacc[1][r];
    if (hi == 0) rbuf[12288 + qq * 32 + l31] = lsum;
  }
  __syncthreads();
  if (kh == 0) {
    const float* p = rbuf + qq * 3072 + lane;
#pragma unroll
    for (int r = 0; r < 16; ++r) oacc[0][r] += p[r * 64];
#pragma unroll
    for (int r = 0; r < 16; ++r) oacc[1][r] += p[(16 + r) * 64];
    const float ltot = lsum + rbuf[12288 + qq * 32 + l31];
    // reshape 1/l from per-qrow(l31) scalar to C-row layout via LDS
    float* lrow = rbuf + 12800 + qq * 32;
    if (hi == 0) lrow[l31] = __builtin_amdgcn_rcpf(ltot);
    f32x4 rl[4];
#pragma unroll
    for (int a = 0; a < 4; ++a)
      rl[a] = *(const f32x4*)(&lrow[a * 8 + hi * 4]);
#pragma unroll
    for (int dsub = 0; dsub < 2; ++dsub) {
      const int col = h * 64 + dsub * 32 + l31;
#pragma unroll
      for (int r = 0; r < 16; ++r) {
        const int row = q0 + qq * 32 + (r & 3) + 8 * (r >> 2) + 4 * hi;
        Op[((size_t)b * Ss + row) * Dd + col] =
            bfc(oacc[dsub][r] * rl[r >> 2][r & 3]);
      }
    }
  }
}

}  // namespace

extern "C" void kernel_launch(void* const* d_in, const int* in_sizes, int n_in,
                              void* d_out, int out_size, void* d_ws, size_t ws_size,
                              hipStream_t stream) {
  (void)in_sizes; (void)n_in; (void)out_size; (void)ws_size;
  const float* v = (const float*)d_in[0];
  const float* q = (const float*)d_in[1];
  const float* k = (const float*)d_in[2];
  const float* mask = (const float*)d_in[3];
  const float* Wq = (const float*)d_in[4];
  const float* bq = (const float*)d_in[5];
  const float* Wv = (const float*)d_in[6];
  const float* bv = (const float*)d_in[7];
  const float* Wo = (const float*)d_in[8];
  const float* bo = (const float*)d_in[9];
  float* out = (float*)d_out;

  constexpr size_t MEG = 1024 * 1024;
  u16* ws = (u16*)d_ws;
  u16* WqT = ws;                 // 1M u16
  u16* WvT = ws + 1 * MEG;       // 1M
  u16* WoT = ws + 2 * MEG;       // 1M
  u16* AO  = ws + 3 * MEG;       // 4M (former qb slot)
  u16* Qp  = ws + 15 * MEG;      // 4M
  u16* Kp  = ws + 19 * MEG;      // 4M
  u16* VpT = ws + 23 * MEG;      // 4M  V^T: [1024][4096], masked rows zeroed

  prep<<<dim3(3072), 256, 0, stream>>>(Wq, Wv, Wo, ws);
  // NOTE: reference projects K with the QUERY weights (wQuery(k)).
  proj_qkv<<<dim3(1536), 256, 0, stream>>>(q, k, v, WqT, WvT, bq, bv, mask,
                                           Qp, Kp, VpT);
  attn32<<<dim3(16, 32), 512, 0, stream>>>(Qp, Kp, VpT, mask, AO);
  gemm_o<<<dim3(1024), 256, 0, stream>>>(AO, WoT, bo, out);
}

// Round 21
// 119.259 us; speedup vs baseline: 1.4520x; 1.4520x over previous
//
#include <hip/hip_runtime.h>
#include <cstddef>

// MultiHeadAttentionLayer: B=2, S=2048, D=1024, H=16, DEPTH=64
// R20: REVERT to R17 (best measured: 119.27us). R19's fused f32 A-path
//      regressed proj 35->118us (latency-serialized + uncoalesced f32
//      loads + A-panel re-fetch) -- third failure of reg-staged f32->bf16
//      inside a GEMM; the bf16 intermediate + streaming cvt is strictly
//      better. Config: prep(W-transpose + cvt), proj_qkv(bf16, 128x64,
//      grid 1536, 6 blk/CU TLP), attn32(R13 pair-tile, 54us plateau),
//      gemm_o(128x64, 3-deep counted-vmcnt).

namespace {

constexpr int Ss = 2048;
constexpr int Dd = 1024;
constexpr int Mm = 4096;  // B*S
constexpr float QSCALE = 0.18033688f;   // 0.125 / ln2  (base-2 softmax)
constexpr float NEG2 = -1.442695041e9f; // -1e9 / ln2

typedef unsigned short u16;
typedef __attribute__((ext_vector_type(8))) __bf16 bf16x8;
typedef __attribute__((ext_vector_type(4))) float f32x4;
typedef __attribute__((ext_vector_type(16))) float f32x16;
typedef __attribute__((ext_vector_type(4))) unsigned int u32x4;
typedef __attribute__((ext_vector_type(2))) unsigned int u32x2;
typedef __attribute__((ext_vector_type(8))) unsigned short us8;

__device__ __forceinline__ u16 bfc(float f) {
  __bf16 h = (__bf16)f;  // RNE; pairs into v_cvt_pk_bf16_f32
  return __builtin_bit_cast(u16, h);
}
__device__ __forceinline__ unsigned pack2(float lo, float hi) {
  return (unsigned)bfc(lo) | ((unsigned)bfc(hi) << 16);
}

__device__ __forceinline__ void gload_lds16(const void* g, void* l) {
  __builtin_amdgcn_global_load_lds(
      (__attribute__((address_space(1))) void*)g,
      (__attribute__((address_space(3))) void*)l, 16, 0, 0);
}

__device__ __forceinline__ f32x4 mfma16(bf16x8 a, bf16x8 b, f32x4 c) {
  return __builtin_amdgcn_mfma_f32_16x16x32_bf16(a, b, c, 0, 0, 0);
}
__device__ __forceinline__ f32x16 mfma32(bf16x8 a, bf16x8 b, f32x16 c) {
  return __builtin_amdgcn_mfma_f32_32x32x16_bf16(a, b, c, 0, 0, 0);
}
__device__ __forceinline__ float exp2_fast(float x) {
  return __builtin_amdgcn_exp2f(x);
}

__device__ __forceinline__ void pl32swap(unsigned& a, unsigned& b) {
#if __has_builtin(__builtin_amdgcn_permlane32_swap)
  u32x2 r = __builtin_amdgcn_permlane32_swap(a, b, false, false);
  a = r[0];
  b = r[1];
#else
  unsigned ax = (unsigned)__shfl_xor((int)a, 32);
  unsigned bx = (unsigned)__shfl_xor((int)b, 32);
  bool hi = (threadIdx.x & 63) >= 32;
  unsigned na = hi ? bx : a;
  unsigned nb = hi ? b : ax;
  a = na;
  b = nb;
#endif
}

// counted-vmcnt barrier (T4)
#define PIPE_BARRIER_V(N)                                  \
  do {                                                     \
    asm volatile("s_waitcnt vmcnt(" #N ")" ::: "memory");  \
    __builtin_amdgcn_sched_barrier(0);                     \
    __builtin_amdgcn_s_barrier();                          \
    __builtin_amdgcn_sched_barrier(0);                     \
  } while (0)

// swizzled u16 index within a [rows][64 u16] LDS tile (128B rows, 16B chunks)
__device__ __forceinline__ int swz(int row, int col) {
  return row * 64 + ((((col >> 3) ^ (row & 7)) << 3) | (col & 7));
}
// pre-swizzled source column for global_load_lds staging of 8 rows
__device__ __forceinline__ int src_col(int lane) {
  return ((lane & 7) ^ (lane >> 3)) * 8;
}

// ---------------------------------------------------------------- prep
// blk < 3072: W transpose (f32 KxN -> bf16 NxK), 3 weights x 32x32 tiles.
// blk >= 3072: q/k/v f32 -> bf16 streaming convert.
__global__ __launch_bounds__(256) void prep(const float* __restrict__ W0,
                                            const float* __restrict__ W1,
                                            const float* __restrict__ W2,
                                            const float* __restrict__ q,
                                            const float* __restrict__ k,
                                            const float* __restrict__ v,
                                            u16* __restrict__ wsbase,
                                            u16* __restrict__ qb,
                                            u16* __restrict__ kb,
                                            u16* __restrict__ vb) {
  __shared__ float tile[32][33];
  const int blk = (int)blockIdx.x;
  const int tid = threadIdx.x;
  if (blk < 3072) {
    const int z = blk >> 10;
    const int rem = blk & 1023;
    const int n0 = (rem & 31) * 32;
    const int k0 = (rem >> 5) * 32;
    const float* W = (z == 0) ? W0 : (z == 1) ? W1 : W2;
    u16* WT = wsbase + (size_t)z * (1024 * 1024);
    const int tx = tid & 31;
    const int ty = tid >> 5;
#pragma unroll
    for (int i = 0; i < 4; ++i)
      tile[ty + i * 8][tx] = W[(size_t)(k0 + ty + i * 8) * 1024 + n0 + tx];
    __syncthreads();
    const int r = tid >> 3;
    const int c4 = (tid & 7) * 4;
    ushort4 o4 = make_ushort4(bfc(tile[c4 + 0][r]), bfc(tile[c4 + 1][r]),
                              bfc(tile[c4 + 2][r]), bfc(tile[c4 + 3][r]));
    *(ushort4*)(&WT[(size_t)(n0 + r) * 1024 + k0 + c4]) = o4;
  } else {
    const int e = blk - 3072;           // 0..6143
    const int which = e >> 11;
    const int b2 = e & 2047;
    const float* src = (which == 0) ? q : (which == 1) ? k : v;
    u16* dst = (which == 0) ? qb : (which == 1) ? kb : vb;
    const int base = (b2 * 256 + tid) * 8;
    const float4 a = *(const float4*)(src + base);
    const float4 b = *(const float4*)(src + base + 4);
    us8 o;
    o[0] = bfc(a.x); o[1] = bfc(a.y); o[2] = bfc(a.z); o[3] = bfc(a.w);
    o[4] = bfc(b.x); o[5] = bfc(b.y); o[6] = bfc(b.z); o[7] = bfc(b.w);
    *(us8*)(dst + base) = o;
  }
}

// ---------------------------------------------------------------- fused QKV projection
// Pure-bf16 GEMM, 128x64 tiles, grid 1536 (6 blocks/CU capable), simple
// 2-barrier loop (TLP does the overlap). Panel-grouped XCD swizzle.
// z==2 (V): masked tokens' rows are ZEROED (mask folded into V).
__global__ __launch_bounds__(256) void proj_qkv(
    const u16* __restrict__ qb, const u16* __restrict__ kb,
    const u16* __restrict__ vb, const u16* __restrict__ WqT,
    const u16* __restrict__ WvT, const float* __restrict__ bq,
    const float* __restrict__ bv, const float* __restrict__ maskf,
    u16* __restrict__ Qp, u16* __restrict__ Kp, u16* __restrict__ VpT) {
  constexpr int K = 1024, N = 1024, M = 4096;
  __shared__ u16 As[128 * 64];
  __shared__ u16 Bs[64 * 64];
  const int lin = (int)blockIdx.x;        // 0..1535
  const int xcd = lin & 7;
  const int j = lin >> 3;                 // 0..191
  const int panel = xcd * 12 + (j >> 4);  // 0..95 (bijective: 12 panels/XCD)
  const int ntile = j & 15;               // 0..15
  const int z = panel >> 5;               // 0..2
  const int mtile = panel & 31;
  const int n0 = ntile * 64;
  const int m0 = mtile * 128;

  const u16* A = (z == 0) ? qb : (z == 1) ? kb : vb;
  const u16* Bt = (z == 2) ? WvT : WqT;
  const float* bias = (z == 2) ? bv : bq;
  const float cscale = (z == 0) ? QSCALE : 1.0f;

  const int tid = threadIdx.x;
  const int wid = tid >> 6;
  const int lane = tid & 63;
  const int g = lane >> 4;
  const int lr = lane & 15;

  const f32x4 zero = {0.f, 0.f, 0.f, 0.f};
  f32x4 acc[2][4];
#pragma unroll
  for (int m = 0; m < 2; ++m)
#pragma unroll
    for (int n = 0; n < 4; ++n) acc[m][n] = zero;

  for (int kt = 0; kt < 16; ++kt) {
#pragma unroll
    for (int jj = 0; jj < 4; ++jj) {
      int rb = (wid * 4 + jj) * 8;
      gload_lds16(&A[(size_t)(m0 + rb + (lane >> 3)) * K + kt * 64 + src_col(lane)],
                  &As[rb * 64]);
    }
#pragma unroll
    for (int jj = 0; jj < 2; ++jj) {
      int rb = (wid * 2 + jj) * 8;
      gload_lds16(&Bt[(size_t)(n0 + rb + (lane >> 3)) * K + kt * 64 + src_col(lane)],
                  &Bs[rb * 64]);
    }
    __syncthreads();
#pragma unroll
    for (int kk = 0; kk < 2; ++kk) {
      bf16x8 a[2], b[4];
#pragma unroll
      for (int m = 0; m < 2; ++m)
        a[m] = *(const bf16x8*)(&As[swz(wid * 32 + m * 16 + lr, kk * 32 + g * 8)]);
#pragma unroll
      for (int n = 0; n < 4; ++n)
        b[n] = *(const bf16x8*)(&Bs[swz(n * 16 + lr, kk * 32 + g * 8)]);
#pragma unroll
      for (int m = 0; m < 2; ++m)
#pragma unroll
        for (int n = 0; n < 4; ++n) acc[m][n] = mfma16(a[m], b[n], acc[m][n]);
    }
    __syncthreads();
  }

#pragma unroll
  for (int n = 0; n < 4; ++n) {
    const int col = n0 + n * 16 + lr;
    const float bv_ = bias[col];
#pragma unroll
    for (int m = 0; m < 2; ++m) {
      const int rowb = m0 + wid * 32 + m * 16 + g * 4;
      if (z == 2) {
        const f32x4 mk = *(const f32x4*)(&maskf[rowb]);
        ushort4 o4;
        o4.x = (mk[0] != 0.f) ? (u16)0 : bfc(acc[m][n][0] + bv_);
        o4.y = (mk[1] != 0.f) ? (u16)0 : bfc(acc[m][n][1] + bv_);
        o4.z = (mk[2] != 0.f) ? (u16)0 : bfc(acc[m][n][2] + bv_);
        o4.w = (mk[3] != 0.f) ? (u16)0 : bfc(acc[m][n][3] + bv_);
        *(ushort4*)(&VpT[(size_t)col * M + rowb]) = o4;
      } else {
        u16* Cp = (z == 0) ? Qp : Kp;
#pragma unroll
        for (int r = 0; r < 4; ++r)
          Cp[(size_t)(rowb + r) * N + col] = bfc((acc[m][n][r] + bv_) * cscale);
      }
    }
  }
}

// ---------------------------------------------------------------- O-GEMM
// out = AO @ WoT^T + bo (f32). 128x64 tile; 3-deep counted-vmcnt pipeline.
__global__ __launch_bounds__(256) void gemm_o(const u16* __restrict__ Ap,
                                              const u16* __restrict__ Bt,
                                              const float* __restrict__ bias,
                                              float* __restrict__ Cp) {
  constexpr int K = 1024, N = 1024;
  __shared__ u16 As[3][128 * 64];
  __shared__ u16 Bs[3][64 * 64];
  const int lin = (int)blockIdx.x;       // 0..511
  const int xcd = lin & 7;
  const int j = lin >> 3;                // 0..63
  const int mtile = xcd * 4 + (j >> 4);  // 0..31
  const int ntile = j & 15;
  const int n0 = ntile * 64;
  const int m0 = mtile * 128;

  const int tid = threadIdx.x;
  const int wid = tid >> 6;
  const int lane = tid & 63;
  const int g = lane >> 4;
  const int lr = lane & 15;

  const f32x4 zero = {0.f, 0.f, 0.f, 0.f};
  f32x4 acc[2][4];
#pragma unroll
  for (int m = 0; m < 2; ++m)
#pragma unroll
    for (int n = 0; n < 4; ++n) acc[m][n] = zero;

  auto stage = [&](int kt, u16* as, u16* bs) {
#pragma unroll
    for (int jj = 0; jj < 4; ++jj) {
      int rb = (wid * 4 + jj) * 8;
      gload_lds16(&Ap[(size_t)(m0 + rb + (lane >> 3)) * K + kt * 64 + src_col(lane)],
                  as + rb * 64);
    }
#pragma unroll
    for (int jj = 0; jj < 2; ++jj) {
      int rb = (wid * 2 + jj) * 8;
      gload_lds16(&Bt[(size_t)(n0 + rb + (lane >> 3)) * K + kt * 64 + src_col(lane)],
                  bs + rb * 64);
    }
  };

  stage(0, As[0], Bs[0]);  // 6 loads in flight
  stage(1, As[1], Bs[1]);  // 12

  int b0 = 0;
  for (int kt = 0; kt < 16; ++kt) {
    if (kt < 15) PIPE_BARRIER_V(6);  // drain tile kt, keep kt+1 in flight
    else         PIPE_BARRIER_V(0);
    if (kt + 2 < 16) {
      int b2 = b0 + 2; if (b2 >= 3) b2 -= 3;
      stage(kt + 2, As[b2], Bs[b2]);
    }
    const u16* as = As[b0];
    const u16* bs = Bs[b0];
#pragma unroll
    for (int kk = 0; kk < 2; ++kk) {
      bf16x8 a[2], b[4];
#pragma unroll
      for (int m = 0; m < 2; ++m)
        a[m] = *(const bf16x8*)(&as[swz(wid * 32 + m * 16 + lr, kk * 32 + g * 8)]);
#pragma unroll
      for (int n = 0; n < 4; ++n)
        b[n] = *(const bf16x8*)(&bs[swz(n * 16 + lr, kk * 32 + g * 8)]);
#pragma unroll
      for (int m = 0; m < 2; ++m)
#pragma unroll
        for (int n = 0; n < 4; ++n) acc[m][n] = mfma16(a[m], b[n], acc[m][n]);
    }
    b0 = (b0 == 2) ? 0 : b0 + 1;
  }
#pragma unroll
  for (int n = 0; n < 4; ++n) {
    const int col = n0 + n * 16 + lr;
    const float bv_ = bias[col];
#pragma unroll
    for (int m = 0; m < 2; ++m) {
      const int rowb = m0 + wid * 32 + m * 16 + g * 4;
#pragma unroll
      for (int r = 0; r < 4; ++r)
        Cp[(size_t)(rowb + r) * N + col] = acc[m][n][r] + bv_;
    }
  }
}

// ---------------------------------------------------------------- attention
// 8-wave key-split flash attention, PAIR-TILE iterations (16 barriers).
// Block = 128 q-rows (512 thr); wave (qq=wid&3, kh=wid>>2) = 32 q-rows x
// 32-key half per 64-key tile. Mask bias folded into QK C-init (base-2);
// p underflows to 0 for masked keys; l = VALU row-sum tree. 4-buffer LDS.
__global__ __launch_bounds__(512) void attn32(const u16* __restrict__ Qp,
                                              const u16* __restrict__ Kp,
                                              const u16* __restrict__ VpT,
                                              const float* __restrict__ mask,
                                              u16* __restrict__ Op) {
  __shared__ u16 smem[8 * 64 * 64];  // 64 KB: K bufs 0..3, V bufs 4..7 (x4096 u16)
  __shared__ float msall[Ss];        // 8 KB mask * NEG2
  const int tid = threadIdx.x;
  const int wid = tid >> 6;          // 0..7
  const int lane = tid & 63;
  const int l31 = lane & 31;
  const int hi = lane >> 5;
  const int qq = wid & 3;
  const int kh = wid >> 2;           // key-half this wave owns
  const int lin = (int)(blockIdx.x + (blockIdx.y << 4));  // grid (16,32)
  const int wl = (lin & 7) * 64 + (lin >> 3);             // XCD-bijective
  const int qt = wl & 15;
  const int bh = wl >> 4;
  const int b = bh >> 4;
  const int h = bh & 15;
  const int q0 = qt * 128;
  const size_t base = ((size_t)b * Ss) * Dd + (size_t)h * 64;
  const size_t vbase = (size_t)h * 64 * Mm + (size_t)b * Ss;
  const int qrow = q0 + qq * 32 + l31;

  auto stageKV = [&](int t, int buf) {
    const int key0 = t * 64;
    const int rb = wid * 8;  // 8 waves x 8 rows = 64 rows each of K and V^T
    gload_lds16(&Kp[base + (size_t)(key0 + rb + (lane >> 3)) * Dd + src_col(lane)],
                smem + buf * 4096 + rb * 64);
    gload_lds16(&VpT[vbase + (size_t)(rb + (lane >> 3)) * Mm + key0 + src_col(lane)],
                smem + (4 + buf) * 4096 + rb * 64);
  };

  // prologue: mask + qf loads (drained here), then staging (stays in flight)
  const float4 mk = *(const float4*)(&mask[(size_t)b * Ss + tid * 4]);
  bf16x8 qf[4];
#pragma unroll
  for (int d = 0; d < 4; ++d)
    qf[d] = *(const bf16x8*)(&Qp[base + (size_t)qrow * Dd + d * 16 + hi * 8]);

  stageKV(0, 0);  // tiles 0,1 -> bufs 0,1 (4 loads in flight)
  stageKV(1, 1);

  {
    f32x4 s = {mk.x * NEG2, mk.y * NEG2, mk.z * NEG2, mk.w * NEG2};
    *(f32x4*)(&msall[tid * 4]) = s;
  }
  asm volatile("s_waitcnt lgkmcnt(0)" ::: "memory");
  __builtin_amdgcn_sched_barrier(0);
  __builtin_amdgcn_s_barrier();
  __builtin_amdgcn_sched_barrier(0);

  f32x16 oacc[2];
#pragma unroll
  for (int i = 0; i < 2; ++i)
#pragma unroll
    for (int r = 0; r < 16; ++r) oacc[i][r] = 0.f;
  float lsum = 0.f;

  for (int i = 0; i < 16; ++i) {
    // pair i's loads were issued a full compute phase ago -> cheap drain
    PIPE_BARRIER_V(0);
    if (i < 15) {
      stageKV(2 * i + 2, (2 * i + 2) & 3);  // bufs freed by iter i-1 (barrier-proven)
      stageKV(2 * i + 3, (2 * i + 3) & 3);
    }
#pragma unroll
    for (int u = 0; u < 2; ++u) {
      const int t = 2 * i + u;
      const int buf = t & 3;
      const u16* ks = smem + buf * 4096;
      const u16* vt = smem + (4 + buf) * 4096;
      const float* msp = &msall[t * 64 + kh * 32];

      // S^T = K Q^T with C-init = mask bias (broadcast f32x4 reads).
      // key(r,hi) = kh*32 + (r&3) + 8*(r>>2) + 4*hi  (r = a*4+j)
      f32x16 sacc;
#pragma unroll
      for (int a = 0; a < 4; ++a) {
        const f32x4 mv = *(const f32x4*)(&msp[a * 8 + hi * 4]);
#pragma unroll
        for (int jj = 0; jj < 4; ++jj) sacc[a * 4 + jj] = mv[jj];
      }
      __builtin_amdgcn_s_setprio(1);
#pragma unroll
      for (int d = 0; d < 4; ++d) {
        bf16x8 kf = *(const bf16x8*)(&ks[swz(kh * 32 + l31, d * 16 + hi * 8)]);
        sacc = mfma32(kf, qf[d], sacc);
      }
      __builtin_amdgcn_s_setprio(0);

      // p = exp2(s + bias): masked keys -> exactly 0
#pragma unroll
      for (int r = 0; r < 16; ++r) sacc[r] = exp2_fast(sacc[r]);

      // l: VALU row-sum tree (qrow = l31) + cross-hi shuffle
      {
        float sm[8];
#pragma unroll
        for (int r = 0; r < 8; ++r) sm[r] = sacc[r] + sacc[r + 8];
#pragma unroll
        for (int s = 4; s >= 1; s >>= 1)
#pragma unroll
          for (int r = 0; r < s; ++r) sm[r] += sm[r + s];
        lsum += sm[0] + __shfl_xor(sm[0], 32);
      }

      // pack P -> bf16 A-fragments (T12)
      bf16x8 pa[2];
#pragma unroll
      for (int slot = 0; slot < 2; ++slot) {
        const int bse = slot * 8;
        unsigned A0 = pack2(sacc[bse + 0], sacc[bse + 1]);
        unsigned A1 = pack2(sacc[bse + 2], sacc[bse + 3]);
        unsigned B0 = pack2(sacc[bse + 4], sacc[bse + 5]);
        unsigned B1 = pack2(sacc[bse + 6], sacc[bse + 7]);
        pl32swap(A0, B0);
        pl32swap(A1, B1);
        u32x4 w = {A0, A1, B0, B1};
        pa[slot] = __builtin_bit_cast(bf16x8, w);
      }

      // O += P V
      __builtin_amdgcn_s_setprio(1);
#pragma unroll
      for (int slot = 0; slot < 2; ++slot)
#pragma unroll
        for (int dsub = 0; dsub < 2; ++dsub) {
          bf16x8 vf = *(const bf16x8*)(
              &vt[swz(dsub * 32 + l31, kh * 32 + slot * 16 + hi * 8)]);
          oacc[dsub] = mfma32(pa[slot], vf, oacc[dsub]);
        }
      __builtin_amdgcn_s_setprio(0);
    }
  }

  // cross-wave (kh) combine through the dead K/V buffers.
  __syncthreads();
  float* rbuf = (float*)smem;   // 16384 floats available
  if (kh == 1) {
    float* p = rbuf + qq * 3072 + lane;
#pragma unroll
    for (int r = 0; r < 16; ++r) p[r * 64] = oacc[0][r];
#pragma unroll
    for (int r = 0; r < 16; ++r) p[(16 + r) * 64] = oacc[1][r];
    if (hi == 0) rbuf[12288 + qq * 32 + l31] = lsum;
  }
  __syncthreads();
  if (kh == 0) {
    const float* p = rbuf + qq * 3072 + lane;
#pragma unroll
    for (int r = 0; r < 16; ++r) oacc[0][r] += p[r * 64];
#pragma unroll
    for (int r = 0; r < 16; ++r) oacc[1][r] += p[(16 + r) * 64];
    const float ltot = lsum + rbuf[12288 + qq * 32 + l31];
    // reshape 1/l from per-qrow(l31) scalar to C-row layout via LDS
    float* lrow = rbuf + 12800 + qq * 32;
    if (hi == 0) lrow[l31] = __builtin_amdgcn_rcpf(ltot);
    f32x4 rl[4];
#pragma unroll
    for (int a = 0; a < 4; ++a)
      rl[a] = *(const f32x4*)(&lrow[a * 8 + hi * 4]);
#pragma unroll
    for (int dsub = 0; dsub < 2; ++dsub) {
      const int col = h * 64 + dsub * 32 + l31;
#pragma unroll
      for (int r = 0; r < 16; ++r) {
        const int row = q0 + qq * 32 + (r & 3) + 8 * (r >> 2) + 4 * hi;
        Op[((size_t)b * Ss + row) * Dd + col] =
            bfc(oacc[dsub][r] * rl[r >> 2][r & 3]);
      }
    }
  }
}

}  // namespace

extern "C" void kernel_launch(void* const* d_in, const int* in_sizes, int n_in,
                              void* d_out, int out_size, void* d_ws, size_t ws_size,
                              hipStream_t stream) {
  (void)in_sizes; (void)n_in; (void)out_size; (void)ws_size;
  const float* v = (const float*)d_in[0];
  const float* q = (const float*)d_in[1];
  const float* k = (const float*)d_in[2];
  const float* mask = (const float*)d_in[3];
  const float* Wq = (const float*)d_in[4];
  const float* bq = (const float*)d_in[5];
  const float* Wv = (const float*)d_in[6];
  const float* bv = (const float*)d_in[7];
  const float* Wo = (const float*)d_in[8];
  const float* bo = (const float*)d_in[9];
  float* out = (float*)d_out;

  constexpr size_t MEG = 1024 * 1024;
  u16* ws = (u16*)d_ws;
  u16* WqT = ws;                 // 1M u16
  u16* WvT = ws + 1 * MEG;       // 1M
  u16* WoT = ws + 2 * MEG;       // 1M
  u16* qb  = ws + 3 * MEG;       // 4M (aliased by AO later)
  u16* kb  = ws + 7 * MEG;       // 4M
  u16* vb  = ws + 11 * MEG;      // 4M
  u16* Qp  = ws + 15 * MEG;      // 4M
  u16* Kp  = ws + 19 * MEG;      // 4M
  u16* VpT = ws + 23 * MEG;      // 4M  V^T: [1024][4096], masked rows zeroed
  u16* AO  = qb;                 // alias: qb dead after proj_qkv

  prep<<<dim3(3072 + 6144), 256, 0, stream>>>(Wq, Wv, Wo, q, k, v, ws, qb, kb, vb);
  // NOTE: reference projects K with the QUERY weights (wQuery(k)).
  proj_qkv<<<dim3(1536), 256, 0, stream>>>(qb, kb, vb, WqT, WvT, bq, bv, mask,
                                           Qp, Kp, VpT);
  attn32<<<dim3(16, 32), 512, 0, stream>>>(Qp, Kp, VpT, mask, AO);
  gemm_o<<<dim3(512), 256, 0, stream>>>(AO, WoT, bo, out);
}